// Round 7
// baseline (233.254 us; speedup 1.0000x reference)
//
#include <hip/hip_runtime.h>
#include <cstdint>
#include <cstddef>
#include <math.h>

// Problem constants: N=2, L=S=2048, Hd=512, H=8, E=64, TOPK=32
#define NH     8
#define EH     64
#define HD     512
#define NBATCH 2
#define LSEQ   2048
#define TK     32

// ws layout: q f32 [0, 2097152) | k f32 row-major [2097152, 4194304) |
//            v f32 [4194304, 6291456) | khi bf16-frag u16 at ws+6291456 (4 MiB)
// khi: per head 128 key-tiles x 2 ksteps x 64 lanes x 8 u16 (= 131072 u16/head).
// out layout (f32): V[2][2048][512] then A[2][8][2048][2048]
// A is ZEROED by proj_kernel (interleaved streaming stores); attn scatters the
// 32 weights per row on top (kernel-boundary ordering makes this race-free).

using f32x4  = __attribute__((ext_vector_type(4))) float;
using bf16x8 = __attribute__((ext_vector_type(8))) short;
using u16x8  = __attribute__((ext_vector_type(8))) unsigned short;
using u16x4  = __attribute__((ext_vector_type(4))) unsigned short;

#define A_TOTAL4 16777216ull   // 2*8*2048*2048 / 4 float4s of A
#define PROJ_THREADS 393216ull // 1536 blocks * 256

__device__ __forceinline__ unsigned short f2b(float f) {   // f32 -> bf16 RNE bits
    unsigned u = __float_as_uint(f);
    return (unsigned short)((u + 0x7FFFu + ((u >> 16) & 1u)) >> 16);
}
__device__ __forceinline__ unsigned f2key(float f) {       // order-preserving u32
    unsigned u = __float_as_uint(f);
    return (u & 0x80000000u) ? ~u : (u | 0x80000000u);
}
__device__ __forceinline__ float key2f(unsigned k) {
    return __uint_as_float((k & 0x80000000u) ? (k ^ 0x80000000u) : ~k);
}
__device__ __forceinline__ unsigned umax2(unsigned a, unsigned b) { return a > b ? a : b; }

// ---------------------------------------------------------------------------
// Kernel 1: fused projections out = X @ W^T + b (row-major head-major);
// z==1 also emits khi (bf16, MFMA B-frag order, coalesced ushort8 stores).
// NEW: zero-fills all of A via interleaved grid-stride float4 stores (3 per
// k-chunk), exploiting proj's otherwise-idle HBM write bandwidth.
// ---------------------------------------------------------------------------
__global__ __launch_bounds__(256) void proj_kernel(
    const float* __restrict__ Xq, const float* __restrict__ Xk, const float* __restrict__ Xv,
    const float* __restrict__ Wq, const float* __restrict__ Bq,
    const float* __restrict__ Wk, const float* __restrict__ Bk,
    const float* __restrict__ Wv, const float* __restrict__ Bv,
    float* __restrict__ ws, float* __restrict__ outA)
{
    const int z = blockIdx.z;
    const float* X = (z == 0) ? Xq : (z == 1) ? Xk : Xv;
    const float* W = (z == 0) ? Wq : (z == 1) ? Wk : Wv;
    const float* B = (z == 0) ? Bq : (z == 1) ? Bk : Bv;
    float* out = ws + (size_t)z * 2097152;
    unsigned short* khi = (unsigned short*)(ws + 6291456);

    __shared__ float4 Xs[64 * 8];
    __shared__ float4 Ws[64 * 8];
    __shared__ unsigned short kst[64 * 72];   // bf16 tile stage (stride 72 -> 16B align)

    const int tid = threadIdx.x;
    const int tx = tid & 15, ty = tid >> 4;
    const int m0 = blockIdx.x * 64, n0 = blockIdx.y * 64;
    const int lin = (blockIdx.z * gridDim.y + blockIdx.y) * gridDim.x + blockIdx.x;
    const size_t gtid = (size_t)lin * 256 + tid;
    float4* outA4 = (float4*)outA;
    const float4 z4 = make_float4(0.f, 0.f, 0.f, 0.f);

    float acc[4][4];
    #pragma unroll
    for (int i = 0; i < 4; ++i)
        #pragma unroll
        for (int j = 0; j < 4; ++j) acc[i][j] = 0.f;

    int cc = 0;
    for (int k0 = 0; k0 < HD; k0 += 32, ++cc) {
        #pragma unroll
        for (int it = 0; it < 2; ++it) {
            int f = tid + it * 256;
            int row = f >> 3, c = f & 7;
            int cs = c ^ ((row >> 2) & 7);
            Xs[row * 8 + cs] = *(const float4*)&X[(size_t)(m0 + row) * HD + k0 + c * 4];
            Ws[row * 8 + cs] = *(const float4*)&W[(size_t)(n0 + row) * HD + k0 + c * 4];
        }
        // interleaved A-zero slice: 3 float4 stores per chunk (fire-and-forget)
        #pragma unroll
        for (int j = 0; j < 3; ++j) {
            size_t zi = gtid + (size_t)(cc * 3 + j) * PROJ_THREADS;
            if (zi < A_TOTAL4) outA4[zi] = z4;
        }
        __syncthreads();
        #pragma unroll
        for (int c = 0; c < 8; ++c) {
            float4 av[4], bv4[4];
            #pragma unroll
            for (int i = 0; i < 4; ++i) { int r = ty * 4 + i; av[i]  = Xs[r * 8 + (c ^ ((r >> 2) & 7))]; }
            #pragma unroll
            for (int j = 0; j < 4; ++j) { int r = tx * 4 + j; bv4[j] = Ws[r * 8 + (c ^ ((r >> 2) & 7))]; }
            #pragma unroll
            for (int i = 0; i < 4; ++i)
                #pragma unroll
                for (int j = 0; j < 4; ++j) {
                    acc[i][j] = fmaf(av[i].x, bv4[j].x, acc[i][j]);
                    acc[i][j] = fmaf(av[i].y, bv4[j].y, acc[i][j]);
                    acc[i][j] = fmaf(av[i].z, bv4[j].z, acc[i][j]);
                    acc[i][j] = fmaf(av[i].w, bv4[j].w, acc[i][j]);
                }
        }
        __syncthreads();
    }

    #pragma unroll
    for (int j = 0; j < 4; ++j) {
        int o = n0 + tx * 4 + j;
        float bb = B[o];
        int h = o >> 6, e = o & 63;
        #pragma unroll
        for (int i = 0; i < 4; ++i) {
            int m = m0 + ty * 4 + i;
            int n = m >> 11, s = m & 2047;
            float val = acc[i][j] + bb;
            int head = n * NH + h;
            out[(size_t)head * 131072 + (size_t)s * EH + e] = val;
            if (z == 1) kst[(ty * 4 + i) * 72 + e] = f2b(val);
        }
    }

    if (z == 1) {
        __syncthreads();
        const int head = (m0 >> 11) * NH + (n0 >> 6);
        const int kt0  = (m0 & 2047) >> 4;
        #pragma unroll
        for (int it = 0; it < 2; ++it) {
            int g = tid + it * 256;                 // 512 frags: 4 kt x 2 ks x 64 lanes
            int lane_g = g & 63;
            int rest = g >> 6;
            int kt = rest >> 1, ksb = rest & 1;
            int s_loc = kt * 16 + (lane_g & 15);
            int e0 = ksb * 32 + ((lane_g >> 4) << 3);
            u16x8 vv = *(const u16x8*)&kst[s_loc * 72 + e0];
            size_t idx = ((((size_t)head * 128 + (kt0 + kt)) * 2 + ksb) * 64 + lane_g) * 8;
            *(u16x8*)&khi[idx] = vv;
        }
    }
}

// ---------------------------------------------------------------------------
// Kernel 2: MFMA bf16 approx QK^T -> tau-margin candidates -> exact f32
// rescore -> exact top-32 (u64 bitonic, tie=lowest idx) -> softmax -> A, V.
// Round-7: scores16 in [key][row^(key&12)] layout (b64 frag stores, paired-row
// u32 reads); A epilogue = 32-weight scatter only (A pre-zeroed by proj).
// ---------------------------------------------------------------------------
__device__ __forceinline__ unsigned long long sort64_desc(unsigned long long v, int lane) {
    #pragma unroll
    for (int k = 2; k <= 64; k <<= 1)
        #pragma unroll
        for (int j = k >> 1; j >= 1; j >>= 1) {
            unsigned long long o = __shfl_xor(v, j, 64);
            bool up = ((lane & k) != 0);                 // flipped -> descending
            bool keepmin = (((lane & j) == 0) == up);
            unsigned long long lo = v < o ? v : o;
            unsigned long long hi = v > o ? v : o;
            v = keepmin ? lo : hi;
        }
    return v;
}
__device__ __forceinline__ unsigned long long merge_top64(unsigned long long a, unsigned long long b, int lane) {
    unsigned long long br = __shfl(b, 63 - lane, 64);
    unsigned long long m = a > br ? a : br;
    #pragma unroll
    for (int j = 32; j >= 1; j >>= 1) {
        unsigned long long o = __shfl_xor(m, j, 64);
        bool keepmax = ((lane & j) == 0);
        unsigned long long mx = m > o ? m : o;
        unsigned long long mn = m < o ? m : o;
        m = keepmax ? mx : mn;
    }
    return m;
}

__global__ __launch_bounds__(512, 4) void attn_kernel(
    const float* __restrict__ ws, float* __restrict__ outV, float* __restrict__ outA)
{
    const float* qw = ws;
    const float* kw = ws + 2097152;
    const float* vw = ws + 4194304;
    const unsigned short* khi = (const unsigned short*)(ws + 6291456);

    __shared__ unsigned short scores16[2048 * 16];   // 65536 B, [key][row^(key&12)]
    __shared__ float qs[EH * 16];                    // 4096 B, [e][row]
    __shared__ unsigned short candArr[8 * 256];      // 4096 B

    const int tid  = threadIdx.x;
    const int lane = tid & 63;
    const int uwv  = __builtin_amdgcn_readfirstlane(tid) >> 6;  // wave id (SGPR)

    // XCD swizzle: 2048 blocks, 256/XCD = 2 heads per XCD (working set ~3.5MB in L2)
    unsigned bid = blockIdx.x;
    unsigned id  = (bid & 7u) * 256u + (bid >> 3);
    const int head = (int)(id >> 7);           // n*8+h
    const int l0   = (int)(id & 127u) * 16;
    const size_t headoff = (size_t)head * 131072;

    // stage q: qs[e][row], rows l0..l0+15
    #pragma unroll
    for (int it = 0; it < 2; ++it) {
        int i = tid + it * 512;
        int row = i & 15, e = i >> 4;
        qs[i] = qw[headoff + (size_t)(l0 + row) * EH + e];
    }
    __syncthreads();

    // ---- Phase A: MFMA approx scores -> u16 keys in LDS (b64 frag stores) ----
    {
        bf16x8 afrag[2];
        #pragma unroll
        for (int ks = 0; ks < 2; ++ks)
            #pragma unroll
            for (int j = 0; j < 8; ++j) {
                int e = ks * 32 + ((lane >> 4) << 3) + j;
                afrag[ks][j] = (short)f2b(qs[e * 16 + (lane & 15)]);
            }

        #pragma unroll
        for (int kt = 0; kt < 16; ++kt) {
            f32x4 acc = (f32x4)(0.f);
            int ktg = uwv * 16 + kt;
            #pragma unroll
            for (int ks = 0; ks < 2; ++ks) {
                bf16x8 b = *(const bf16x8*)(khi + (size_t)head * 131072 +
                              ((((size_t)ktg * 2 + ks) * 64 + lane) << 3));
                acc = __builtin_amdgcn_mfma_f32_16x16x32_bf16(afrag[ks], b, acc, 0, 0, 0);
            }
            int key = uwv * 256 + kt * 16 + (lane & 15);
            int rbase = (lane >> 4) << 2;          // C: col=lane&15, row=rbase+reg
            int p = rbase ^ (key & 12);            // bank-spread swizzle (4-mult XOR)
            u16x4 s4;
            #pragma unroll
            for (int reg = 0; reg < 4; ++reg)
                s4[reg] = (unsigned short)(f2key(acc[reg]) >> 16);
            *(u16x4*)&scores16[key * 16 + p] = s4;   // one aligned b64 store
        }
    }
    __syncthreads();

    // ---- Select: wave uwv owns rows 2uwv, 2uwv+1; fully wave-local ----
    unsigned short* cand = candArr + uwv * 256;
    const unsigned long long lmlt = (1ull << lane) - 1ull;
    int selS[2]; float selW[2];

    // read both rows' keys once: u32 = {row r0, row r0+1} u16 pair
    const int r0 = 2 * uwv;
    unsigned pk[32];
    #pragma unroll
    for (int t = 0; t < 32; ++t) {
        int key = t * 64 + lane;
        int p0 = r0 ^ (key & 12);                  // even; pair-adjacent with r0+1
        pk[t] = *(const unsigned*)&scores16[key * 16 + p0];
    }

    #pragma unroll
    for (int rr2 = 0; rr2 < 2; ++rr2) {
        const int lrow = l0 + r0 + rr2;

        // 1. per-lane max over this row's 32 keys
        unsigned mx = 0;
        #pragma unroll
        for (int t = 0; t < 32; ++t) {
            unsigned a = rr2 ? (pk[t] >> 16) : (pk[t] & 0xFFFFu);
            mx = umax2(mx, a);
        }
        // 2. bitonic ascending sort of lane maxima; tau16 = rank-32 (lane 32)
        {
            unsigned v = mx;
            #pragma unroll
            for (int k = 2; k <= 64; k <<= 1)
                #pragma unroll
                for (int j = k >> 1; j >= 1; j >>= 1) {
                    unsigned o = __shfl_xor(v, j);
                    bool up = ((lane & k) == 0);
                    bool keepmin = (((lane & j) == 0) == up);
                    unsigned lo = v < o ? v : o, hi = v > o ? v : o;
                    v = keepmin ? lo : hi;
                }
            mx = __shfl(v, 32);
        }
        const unsigned tau16 = mx;
        const float tauf = key2f(tau16 << 16);
        const unsigned thr16 = f2key(tauf - 0.35f) >> 16;   // margin: bf16+trunc error

        // 3. ballot-prefix compaction (unordered ok; sort settles ties by index)
        int Nc = 0;
        #pragma unroll
        for (int t = 0; t < 32; ++t) {
            unsigned a = rr2 ? (pk[t] >> 16) : (pk[t] & 0xFFFFu);
            bool c = a >= thr16;
            unsigned long long b = __ballot(c);
            if (c) {
                int p = Nc + __popcll(b & lmlt);
                if (p < 256) cand[p] = (unsigned short)(t * 64 + lane);
            }
            Nc += __popcll(b);
        }
        if (Nc > 256) Nc = 256;
        const int nch = (Nc + 63) >> 6;

        // 4. q row via wave-uniform global loads (scalar-friendly broadcast)
        const float* qrow = qw + headoff + (size_t)lrow * EH;
        float4 qv[16];
        #pragma unroll
        for (int c4 = 0; c4 < 16; ++c4) qv[c4] = *(const float4*)&qrow[c4 * 4];

        // 5. exact rescore + exact top-32 via u64 bitonic (desc), chunk-merged
        unsigned long long best = 0ull;
        for (int c = 0; c < nch; ++c) {
            int p = c * 64 + lane;
            bool valid = p < Nc;
            int si = valid ? (int)cand[p] : 0;
            const float* krow = kw + headoff + (size_t)si * EH;
            float sc = 0.f;
            #pragma unroll
            for (int c4 = 0; c4 < 16; ++c4) {      // ascending e: matches round-6
                float4 kv = *(const float4*)&krow[c4 * 4];
                sc = fmaf(qv[c4].x, kv.x, sc);
                sc = fmaf(qv[c4].y, kv.y, sc);
                sc = fmaf(qv[c4].z, kv.z, sc);
                sc = fmaf(qv[c4].w, kv.w, sc);
            }
            unsigned long long comp = valid
                ? ((((unsigned long long)f2key(sc)) << 32) | (unsigned)(~si))
                : 0ull;
            comp = sort64_desc(comp, lane);
            best = (c == 0) ? comp : merge_top64(best, comp, lane);
        }

        // 6. softmax over lanes 0..31 (desc order; lane0 = max)
        unsigned key32 = (unsigned)(best >> 32);
        int si = (int)(~((unsigned)best)) & 2047;
        float sc = key2f(key32);
        float M = __shfl(sc, 0);
        float ee = (lane < TK) ? __expf(0.125f * (sc - M)) : 0.f;
        float Z = ee;
        #pragma unroll
        for (int d = 1; d < 64; d <<= 1) Z += __shfl_xor(Z, d);
        selS[rr2] = si;
        selW[rr2] = ee / Z;
    }

    // ---- Epilogue: A = 32-weight scatter (pre-zeroed by proj) + V rows ----
    #pragma unroll
    for (int rr2 = 0; rr2 < 2; ++rr2) {
        const int lrow = l0 + r0 + rr2;
        float* Arow = outA + ((size_t)head * 2048 + lrow) * 2048;
        if (lane < TK) Arow[selS[rr2]] = selW[rr2];

        // V: broadcast slots via readlane (VALU) -> coalesced loads
        float acc = 0.f;
        int   siv = selS[rr2];
        unsigned wbits = __float_as_uint(selW[rr2]);
        #pragma unroll
        for (int i = 0; i < TK; ++i) {
            int s_i   = __builtin_amdgcn_readlane(siv, i);
            float w_i = __uint_as_float((unsigned)__builtin_amdgcn_readlane((int)wbits, i));
            acc = fmaf(w_i, vw[headoff + (size_t)s_i * EH + lane], acc);
        }
        const int n = head >> 3, h = head & 7;
        outV[((size_t)(n * 2048 + lrow)) * 512 + h * 64 + lane] = acc;
    }
}

// ---------------------------------------------------------------------------
extern "C" void kernel_launch(void* const* d_in, const int* in_sizes, int n_in,
                              void* d_out, int out_size, void* d_ws, size_t ws_size,
                              hipStream_t stream)
{
    (void)in_sizes; (void)n_in; (void)out_size; (void)ws_size;
    const float* q  = (const float*)d_in[0];
    const float* k  = (const float*)d_in[1];
    const float* v  = (const float*)d_in[2];
    const float* Wq = (const float*)d_in[3];
    const float* bq = (const float*)d_in[4];
    const float* Wk = (const float*)d_in[5];
    const float* bk = (const float*)d_in[6];
    const float* Wv = (const float*)d_in[7];
    const float* bv = (const float*)d_in[8];
    float* ws   = (float*)d_ws;  // 28 MiB
    float* outV = (float*)d_out;
    float* outA = outV + (size_t)NBATCH * LSEQ * HD;

    proj_kernel<<<dim3(64, 8, 3), 256, 0, stream>>>(q, k, v, Wq, bq, Wk, bk, Wv, bv, ws, outA);
    attn_kernel<<<dim3(2048, 1, 1), 512, 0, stream>>>(ws, outV, outA);
}

// Round 8
// 224.487 us; speedup vs baseline: 1.0391x; 1.0391x over previous
//
#include <hip/hip_runtime.h>
#include <cstdint>
#include <cstddef>
#include <math.h>

// Problem constants: N=2, L=S=2048, Hd=512, H=8, E=64, TOPK=32
#define NH     8
#define EH     64
#define HD     512
#define NBATCH 2
#define LSEQ   2048
#define TK     32

// ws layout: q f32 [0, 2097152) | k f32 row-major [2097152, 4194304) |
//            v f32 [4194304, 6291456) | khi bf16-frag u16 at ws+6291456 (4 MiB)
// khi: per head 128 key-tiles x 2 ksteps x 64 lanes x 8 u16 (= 131072 u16/head).
// out layout (f32): V[2][2048][512] then A[2][8][2048][2048]

using f32x4  = __attribute__((ext_vector_type(4))) float;
using bf16x8 = __attribute__((ext_vector_type(8))) short;
using u16x8  = __attribute__((ext_vector_type(8))) unsigned short;
using u16x4  = __attribute__((ext_vector_type(4))) unsigned short;

__device__ __forceinline__ unsigned short f2b(float f) {   // f32 -> bf16 RNE bits
    unsigned u = __float_as_uint(f);
    return (unsigned short)((u + 0x7FFFu + ((u >> 16) & 1u)) >> 16);
}
__device__ __forceinline__ unsigned f2key(float f) {       // order-preserving u32
    unsigned u = __float_as_uint(f);
    return (u & 0x80000000u) ? ~u : (u | 0x80000000u);
}
__device__ __forceinline__ float key2f(unsigned k) {
    return __uint_as_float((k & 0x80000000u) ? (k ^ 0x80000000u) : ~k);
}
__device__ __forceinline__ unsigned umax2(unsigned a, unsigned b) { return a > b ? a : b; }
__device__ __forceinline__ int swzA(int r, int c) { return c ^ ((r >> 2) & 7); }
__device__ __forceinline__ int swzB(int r, int c) { return c ^ (((r >> 2) ^ (r >> 5)) & 7); }

// ---------------------------------------------------------------------------
// Kernel 1: fused projections out = X @ W^T + b (row-major head-major);
// 64x128 tile, 4x8 micro-tile (DS:VALU = 144:256 cyc per c-step).
// z==1 also emits khi (bf16, MFMA B-frag order) via LDS restage + coalesced
// ushort8 stores. Grid (64, 4, 3), 256 threads.
// ---------------------------------------------------------------------------
__global__ __launch_bounds__(256, 3) void proj_kernel(
    const float* __restrict__ Xq, const float* __restrict__ Xk, const float* __restrict__ Xv,
    const float* __restrict__ Wq, const float* __restrict__ Bq,
    const float* __restrict__ Wk, const float* __restrict__ Bk,
    const float* __restrict__ Wv, const float* __restrict__ Bv,
    float* __restrict__ ws)
{
    const int z = blockIdx.z;
    const float* X = (z == 0) ? Xq : (z == 1) ? Xk : Xv;
    const float* W = (z == 0) ? Wq : (z == 1) ? Wk : Wv;
    const float* B = (z == 0) ? Bq : (z == 1) ? Bk : Bv;
    float* out = ws + (size_t)z * 2097152;
    unsigned short* khi = (unsigned short*)(ws + 6291456);

    __shared__ float4 Xs[64 * 8];               // 8 KB
    __shared__ float4 Ws[128 * 8];              // 16 KB
    __shared__ unsigned short kst[64 * 136];    // 17408 B (z==1 restage; stride 136 -> 16B align)

    const int tid = threadIdx.x;
    const int tx = tid & 15, ty = tid >> 4;     // 16x16 threads, micro 4 rows x 8 cols
    const int m0 = blockIdx.x * 64, n0 = blockIdx.y * 128;

    float acc[4][8];
    #pragma unroll
    for (int i = 0; i < 4; ++i)
        #pragma unroll
        for (int j = 0; j < 8; ++j) acc[i][j] = 0.f;

    for (int k0 = 0; k0 < HD; k0 += 32) {
        #pragma unroll
        for (int it = 0; it < 2; ++it) {        // X: 512 float4
            int f = tid + it * 256;
            int row = f >> 3, c = f & 7;
            Xs[row * 8 + swzA(row, c)] = *(const float4*)&X[(size_t)(m0 + row) * HD + k0 + c * 4];
        }
        #pragma unroll
        for (int it = 0; it < 4; ++it) {        // W: 1024 float4
            int f = tid + it * 256;
            int row = f >> 3, c = f & 7;
            Ws[row * 8 + swzB(row, c)] = *(const float4*)&W[(size_t)(n0 + row) * HD + k0 + c * 4];
        }
        __syncthreads();
        #pragma unroll
        for (int c = 0; c < 8; ++c) {
            float4 av[4], bv[8];
            #pragma unroll
            for (int i = 0; i < 4; ++i) { int r = ty * 4 + i; av[i] = Xs[r * 8 + swzA(r, c)]; }
            #pragma unroll
            for (int j = 0; j < 8; ++j) { int r = tx * 8 + j; bv[j] = Ws[r * 8 + swzB(r, c)]; }
            #pragma unroll
            for (int i = 0; i < 4; ++i)
                #pragma unroll
                for (int j = 0; j < 8; ++j) {
                    acc[i][j] = fmaf(av[i].x, bv[j].x, acc[i][j]);
                    acc[i][j] = fmaf(av[i].y, bv[j].y, acc[i][j]);
                    acc[i][j] = fmaf(av[i].z, bv[j].z, acc[i][j]);
                    acc[i][j] = fmaf(av[i].w, bv[j].w, acc[i][j]);
                }
        }
        __syncthreads();
    }

    // epilogue: bias + vectorized stores (+ kst bf16 restage for z==1)
    float4 bb[2];
    bb[0] = *(const float4*)&B[n0 + tx * 8 + 0];
    bb[1] = *(const float4*)&B[n0 + tx * 8 + 4];
    #pragma unroll
    for (int i = 0; i < 4; ++i) {
        int m = m0 + ty * 4 + i;
        int n = m >> 11, s = m & 2047;
        #pragma unroll
        for (int jj = 0; jj < 2; ++jj) {
            int o0 = n0 + tx * 8 + jj * 4;
            int head = n * NH + (o0 >> 6), e0 = o0 & 63;
            float4 val;
            val.x = acc[i][jj * 4 + 0] + bb[jj].x;
            val.y = acc[i][jj * 4 + 1] + bb[jj].y;
            val.z = acc[i][jj * 4 + 2] + bb[jj].z;
            val.w = acc[i][jj * 4 + 3] + bb[jj].w;
            *(float4*)&out[(size_t)head * 131072 + (size_t)s * EH + e0] = val;
            if (z == 1) {
                u16x4 b4;
                b4[0] = f2b(val.x); b4[1] = f2b(val.y);
                b4[2] = f2b(val.z); b4[3] = f2b(val.w);
                *(u16x4*)&kst[(ty * 4 + i) * 136 + tx * 8 + jj * 4] = b4;
            }
        }
    }

    if (z == 1) {
        __syncthreads();
        const int base_head = (m0 >> 11) * NH + (n0 >> 6);   // first of 2 heads in tile
        const int kt0 = (m0 & 2047) >> 4;
        #pragma unroll
        for (int it = 0; it < 4; ++it) {
            int g = tid + it * 256;                 // 1024 frags: 2 heads x 4 kt x 2 ks x 64 lanes
            int lane_g = g & 63;
            int rest = g >> 6;                      // 0..15
            int head_loc = rest >> 3, ksb = (rest >> 2) & 1, kt = rest & 3;
            int s_loc = kt * 16 + (lane_g & 15);
            int ecol = head_loc * 64 + ksb * 32 + ((lane_g >> 4) << 3);
            u16x8 vv = *(const u16x8*)&kst[s_loc * 136 + ecol];
            size_t idx = ((((size_t)(base_head + head_loc) * 128 + (kt0 + kt)) * 2 + ksb) * 64 + lane_g) * 8;
            *(u16x8*)&khi[idx] = vv;
        }
    }
}

// ---------------------------------------------------------------------------
// Kernel 2: MFMA bf16 approx QK^T -> tau-margin candidates -> exact f32
// rescore -> exact top-32 (u64 bitonic, tie=lowest idx) -> softmax -> A, V.
// scores16 in [key][row^(key&12)] layout (b64 frag stores, paired-row reads);
// A epilogue = round-6 staged full-row writes (dense 1KB/wave stores).
// ---------------------------------------------------------------------------
__device__ __forceinline__ unsigned long long sort64_desc(unsigned long long v, int lane) {
    #pragma unroll
    for (int k = 2; k <= 64; k <<= 1)
        #pragma unroll
        for (int j = k >> 1; j >= 1; j >>= 1) {
            unsigned long long o = __shfl_xor(v, j, 64);
            bool up = ((lane & k) != 0);                 // flipped -> descending
            bool keepmin = (((lane & j) == 0) == up);
            unsigned long long lo = v < o ? v : o;
            unsigned long long hi = v > o ? v : o;
            v = keepmin ? lo : hi;
        }
    return v;
}
__device__ __forceinline__ unsigned long long merge_top64(unsigned long long a, unsigned long long b, int lane) {
    unsigned long long br = __shfl(b, 63 - lane, 64);
    unsigned long long m = a > br ? a : br;
    #pragma unroll
    for (int j = 32; j >= 1; j >>= 1) {
        unsigned long long o = __shfl_xor(m, j, 64);
        bool keepmax = ((lane & j) == 0);
        unsigned long long mx = m > o ? m : o;
        unsigned long long mn = m < o ? m : o;
        m = keepmax ? mx : mn;
    }
    return m;
}

__global__ __launch_bounds__(512, 4) void attn_kernel(
    const float* __restrict__ ws, float* __restrict__ outV, float* __restrict__ outA)
{
    const float* qw = ws;
    const float* kw = ws + 2097152;
    const float* vw = ws + 4194304;
    const unsigned short* khi = (const unsigned short*)(ws + 6291456);

    __shared__ unsigned short scores16[2048 * 16];   // 65536 B, [key][row^(key&12)]
    __shared__ float qs[EH * 16];                    // 4096 B, [e][row]
    __shared__ unsigned short candArr[8 * 256];      // 4096 B

    const int tid  = threadIdx.x;
    const int lane = tid & 63;
    const int uwv  = __builtin_amdgcn_readfirstlane(tid) >> 6;  // wave id (SGPR)

    // XCD swizzle: 2048 blocks, 256/XCD = 2 heads per XCD (working set ~3.5MB in L2)
    unsigned bid = blockIdx.x;
    unsigned id  = (bid & 7u) * 256u + (bid >> 3);
    const int head = (int)(id >> 7);           // n*8+h
    const int l0   = (int)(id & 127u) * 16;
    const size_t headoff = (size_t)head * 131072;

    // stage q: qs[e][row], rows l0..l0+15
    #pragma unroll
    for (int it = 0; it < 2; ++it) {
        int i = tid + it * 512;
        int row = i & 15, e = i >> 4;
        qs[i] = qw[headoff + (size_t)(l0 + row) * EH + e];
    }
    __syncthreads();

    // ---- Phase A: MFMA approx scores -> u16 keys in LDS (b64 frag stores) ----
    {
        bf16x8 afrag[2];
        #pragma unroll
        for (int ks = 0; ks < 2; ++ks)
            #pragma unroll
            for (int j = 0; j < 8; ++j) {
                int e = ks * 32 + ((lane >> 4) << 3) + j;
                afrag[ks][j] = (short)f2b(qs[e * 16 + (lane & 15)]);
            }

        #pragma unroll
        for (int kt = 0; kt < 16; ++kt) {
            f32x4 acc = (f32x4)(0.f);
            int ktg = uwv * 16 + kt;
            #pragma unroll
            for (int ks = 0; ks < 2; ++ks) {
                bf16x8 b = *(const bf16x8*)(khi + (size_t)head * 131072 +
                              ((((size_t)ktg * 2 + ks) * 64 + lane) << 3));
                acc = __builtin_amdgcn_mfma_f32_16x16x32_bf16(afrag[ks], b, acc, 0, 0, 0);
            }
            int key = uwv * 256 + kt * 16 + (lane & 15);
            int rbase = (lane >> 4) << 2;          // C: col=lane&15, row=rbase+reg
            int p = rbase ^ (key & 12);            // bank-spread swizzle (4-mult XOR)
            u16x4 s4;
            #pragma unroll
            for (int reg = 0; reg < 4; ++reg)
                s4[reg] = (unsigned short)(f2key(acc[reg]) >> 16);
            *(u16x4*)&scores16[key * 16 + p] = s4;   // one aligned b64 store
        }
    }
    __syncthreads();

    // ---- Select: wave uwv owns rows 2uwv, 2uwv+1; fully wave-local ----
    unsigned short* cand = candArr + uwv * 256;
    const unsigned long long lmlt = (1ull << lane) - 1ull;
    int selS[2]; float selW[2];

    // read both rows' keys once: u32 = {row r0, row r0+1} u16 pair
    const int r0 = 2 * uwv;
    unsigned pk[32];
    #pragma unroll
    for (int t = 0; t < 32; ++t) {
        int key = t * 64 + lane;
        int p0 = r0 ^ (key & 12);                  // even; pair-adjacent with r0+1
        pk[t] = *(const unsigned*)&scores16[key * 16 + p0];
    }
    __syncthreads();   // all pk reads done before any wave scribbles abuf below

    #pragma unroll
    for (int rr2 = 0; rr2 < 2; ++rr2) {
        const int lrow = l0 + r0 + rr2;

        // 1. per-lane max over this row's 32 keys
        unsigned mx = 0;
        #pragma unroll
        for (int t = 0; t < 32; ++t) {
            unsigned a = rr2 ? (pk[t] >> 16) : (pk[t] & 0xFFFFu);
            mx = umax2(mx, a);
        }
        // 2. bitonic ascending sort of lane maxima; tau16 = rank-32 (lane 32)
        {
            unsigned v = mx;
            #pragma unroll
            for (int k = 2; k <= 64; k <<= 1)
                #pragma unroll
                for (int j = k >> 1; j >= 1; j >>= 1) {
                    unsigned o = __shfl_xor(v, j);
                    bool up = ((lane & k) == 0);
                    bool keepmin = (((lane & j) == 0) == up);
                    unsigned lo = v < o ? v : o, hi = v > o ? v : o;
                    v = keepmin ? lo : hi;
                }
            mx = __shfl(v, 32);
        }
        const unsigned tau16 = mx;
        const float tauf = key2f(tau16 << 16);
        const unsigned thr16 = f2key(tauf - 0.35f) >> 16;   // margin: bf16+trunc error

        // 3. ballot-prefix compaction (unordered ok; sort settles ties by index)
        int Nc = 0;
        #pragma unroll
        for (int t = 0; t < 32; ++t) {
            unsigned a = rr2 ? (pk[t] >> 16) : (pk[t] & 0xFFFFu);
            bool c = a >= thr16;
            unsigned long long b = __ballot(c);
            if (c) {
                int p = Nc + __popcll(b & lmlt);
                if (p < 256) cand[p] = (unsigned short)(t * 64 + lane);
            }
            Nc += __popcll(b);
        }
        if (Nc > 256) Nc = 256;
        const int nch = (Nc + 63) >> 6;

        // 4. q row via wave-uniform global loads (scalar-friendly broadcast)
        const float* qrow = qw + headoff + (size_t)lrow * EH;
        float4 qv[16];
        #pragma unroll
        for (int c4 = 0; c4 < 16; ++c4) qv[c4] = *(const float4*)&qrow[c4 * 4];

        // 5. exact rescore + exact top-32 via u64 bitonic (desc), chunk-merged
        unsigned long long best = 0ull;
        for (int c = 0; c < nch; ++c) {
            int p = c * 64 + lane;
            bool valid = p < Nc;
            int si = valid ? (int)cand[p] : 0;
            const float* krow = kw + headoff + (size_t)si * EH;
            float sc = 0.f;
            #pragma unroll
            for (int c4 = 0; c4 < 16; ++c4) {      // ascending e: matches round-7
                float4 kv = *(const float4*)&krow[c4 * 4];
                sc = fmaf(qv[c4].x, kv.x, sc);
                sc = fmaf(qv[c4].y, kv.y, sc);
                sc = fmaf(qv[c4].z, kv.z, sc);
                sc = fmaf(qv[c4].w, kv.w, sc);
            }
            unsigned long long comp = valid
                ? ((((unsigned long long)f2key(sc)) << 32) | (unsigned)(~si))
                : 0ull;
            comp = sort64_desc(comp, lane);
            best = (c == 0) ? comp : merge_top64(best, comp, lane);
        }

        // 6. softmax over lanes 0..31 (desc order; lane0 = max)
        unsigned key32 = (unsigned)(best >> 32);
        int si = (int)(~((unsigned)best)) & 2047;
        float sc = key2f(key32);
        float M = __shfl(sc, 0);
        float ee = (lane < TK) ? __expf(0.125f * (sc - M)) : 0.f;
        float Z = ee;
        #pragma unroll
        for (int d = 1; d < 64; d <<= 1) Z += __shfl_xor(Z, d);
        selS[rr2] = si;
        selW[rr2] = ee / Z;
    }

    // ---- Epilogue: A rows staged in wave-private 8KB LDS + V rows ----
    float* abuf = (float*)((char*)scores16 + uwv * 8192);   // wave-private 2048 f32
    #pragma unroll
    for (int rr2 = 0; rr2 < 2; ++rr2) {
        const int lrow = l0 + r0 + rr2;
        float4* ab4 = (float4*)abuf;
        const float4 z4 = make_float4(0.f, 0.f, 0.f, 0.f);
        #pragma unroll
        for (int u = 0; u < 8; ++u) ab4[u * 64 + lane] = z4;
        if (lane < TK) abuf[selS[rr2]] = selW[rr2];          // wave-local scatter
        float* Arow = outA + ((size_t)head * 2048 + lrow) * 2048;
        #pragma unroll
        for (int u = 0; u < 8; ++u)
            *(float4*)&Arow[(u * 64 + lane) * 4] = ab4[u * 64 + lane];

        // V: broadcast slots via readlane (VALU) -> coalesced loads
        float acc = 0.f;
        int   siv = selS[rr2];
        unsigned wbits = __float_as_uint(selW[rr2]);
        #pragma unroll
        for (int i = 0; i < TK; ++i) {
            int s_i   = __builtin_amdgcn_readlane(siv, i);
            float w_i = __uint_as_float((unsigned)__builtin_amdgcn_readlane((int)wbits, i));
            acc = fmaf(w_i, vw[headoff + (size_t)s_i * EH + lane], acc);
        }
        const int n = head >> 3, h = head & 7;
        outV[((size_t)(n * 2048 + lrow)) * 512 + h * 64 + lane] = acc;
    }
}

// ---------------------------------------------------------------------------
extern "C" void kernel_launch(void* const* d_in, const int* in_sizes, int n_in,
                              void* d_out, int out_size, void* d_ws, size_t ws_size,
                              hipStream_t stream)
{
    (void)in_sizes; (void)n_in; (void)out_size; (void)ws_size;
    const float* q  = (const float*)d_in[0];
    const float* k  = (const float*)d_in[1];
    const float* v  = (const float*)d_in[2];
    const float* Wq = (const float*)d_in[3];
    const float* bq = (const float*)d_in[4];
    const float* Wk = (const float*)d_in[5];
    const float* bk = (const float*)d_in[6];
    const float* Wv = (const float*)d_in[7];
    const float* bv = (const float*)d_in[8];
    float* ws   = (float*)d_ws;  // 28 MiB
    float* outV = (float*)d_out;
    float* outA = outV + (size_t)NBATCH * LSEQ * HD;

    proj_kernel<<<dim3(64, 4, 3), 256, 0, stream>>>(q, k, v, Wq, bq, Wk, bk, Wv, bv, ws);
    attn_kernel<<<dim3(2048, 1, 1), 512, 0, stream>>>(ws, outV, outA);
}

// Round 9
// 220.290 us; speedup vs baseline: 1.0588x; 1.0191x over previous
//
#include <hip/hip_runtime.h>
#include <cstdint>
#include <cstddef>
#include <math.h>

// Problem constants: N=2, L=S=2048, Hd=512, H=8, E=64, TOPK=32
#define NH     8
#define EH     64
#define HD     512
#define NBATCH 2
#define LSEQ   2048
#define TK     32

// ws layout: q f32 [0, 2097152) | k f32 row-major [2097152, 4194304) |
//            v f32 [4194304, 6291456) | khi bf16-frag u16 at ws+6291456 (4 MiB)
// khi: per head 128 key-tiles x 2 ksteps x 64 lanes x 8 u16 (= 131072 u16/head).
// out layout (f32): V[2][2048][512] then A[2][8][2048][2048]

using f32x4  = __attribute__((ext_vector_type(4))) float;
using bf16x8 = __attribute__((ext_vector_type(8))) short;
using u16x8  = __attribute__((ext_vector_type(8))) unsigned short;
using u16x4  = __attribute__((ext_vector_type(4))) unsigned short;

__device__ __forceinline__ unsigned short f2b(float f) {   // f32 -> bf16 RNE bits
    unsigned u = __float_as_uint(f);
    return (unsigned short)((u + 0x7FFFu + ((u >> 16) & 1u)) >> 16);
}
__device__ __forceinline__ unsigned f2key(float f) {       // order-preserving u32
    unsigned u = __float_as_uint(f);
    return (u & 0x80000000u) ? ~u : (u | 0x80000000u);
}
__device__ __forceinline__ float key2f(unsigned k) {
    return __uint_as_float((k & 0x80000000u) ? (k ^ 0x80000000u) : ~k);
}
__device__ __forceinline__ unsigned umax2(unsigned a, unsigned b) { return a > b ? a : b; }
__device__ __forceinline__ int swzA(int r, int c) { return c ^ ((r >> 2) & 7); }
__device__ __forceinline__ int swzB(int r, int c) { return c ^ (((r >> 2) ^ (r >> 5)) & 7); }

// ---------------------------------------------------------------------------
// Kernel 1: fused projections out = X @ W^T + b (row-major head-major);
// 64x128 tile, 4x8 micro-tile. z==1 also emits khi (bf16, MFMA B-frag order)
// via LDS restage + coalesced ushort8 stores. Grid (64, 4, 3), 256 threads.
// (unchanged from round 8)
// ---------------------------------------------------------------------------
__global__ __launch_bounds__(256, 3) void proj_kernel(
    const float* __restrict__ Xq, const float* __restrict__ Xk, const float* __restrict__ Xv,
    const float* __restrict__ Wq, const float* __restrict__ Bq,
    const float* __restrict__ Wk, const float* __restrict__ Bk,
    const float* __restrict__ Wv, const float* __restrict__ Bv,
    float* __restrict__ ws)
{
    const int z = blockIdx.z;
    const float* X = (z == 0) ? Xq : (z == 1) ? Xk : Xv;
    const float* W = (z == 0) ? Wq : (z == 1) ? Wk : Wv;
    const float* B = (z == 0) ? Bq : (z == 1) ? Bk : Bv;
    float* out = ws + (size_t)z * 2097152;
    unsigned short* khi = (unsigned short*)(ws + 6291456);

    __shared__ float4 Xs[64 * 8];               // 8 KB
    __shared__ float4 Ws[128 * 8];              // 16 KB
    __shared__ unsigned short kst[64 * 136];    // 17408 B (z==1 restage)

    const int tid = threadIdx.x;
    const int tx = tid & 15, ty = tid >> 4;     // 16x16 threads, micro 4 rows x 8 cols
    const int m0 = blockIdx.x * 64, n0 = blockIdx.y * 128;

    float acc[4][8];
    #pragma unroll
    for (int i = 0; i < 4; ++i)
        #pragma unroll
        for (int j = 0; j < 8; ++j) acc[i][j] = 0.f;

    for (int k0 = 0; k0 < HD; k0 += 32) {
        #pragma unroll
        for (int it = 0; it < 2; ++it) {        // X: 512 float4
            int f = tid + it * 256;
            int row = f >> 3, c = f & 7;
            Xs[row * 8 + swzA(row, c)] = *(const float4*)&X[(size_t)(m0 + row) * HD + k0 + c * 4];
        }
        #pragma unroll
        for (int it = 0; it < 4; ++it) {        // W: 1024 float4
            int f = tid + it * 256;
            int row = f >> 3, c = f & 7;
            Ws[row * 8 + swzB(row, c)] = *(const float4*)&W[(size_t)(n0 + row) * HD + k0 + c * 4];
        }
        __syncthreads();
        #pragma unroll
        for (int c = 0; c < 8; ++c) {
            float4 av[4], bv[8];
            #pragma unroll
            for (int i = 0; i < 4; ++i) { int r = ty * 4 + i; av[i] = Xs[r * 8 + swzA(r, c)]; }
            #pragma unroll
            for (int j = 0; j < 8; ++j) { int r = tx * 8 + j; bv[j] = Ws[r * 8 + swzB(r, c)]; }
            #pragma unroll
            for (int i = 0; i < 4; ++i)
                #pragma unroll
                for (int j = 0; j < 8; ++j) {
                    acc[i][j] = fmaf(av[i].x, bv[j].x, acc[i][j]);
                    acc[i][j] = fmaf(av[i].y, bv[j].y, acc[i][j]);
                    acc[i][j] = fmaf(av[i].z, bv[j].z, acc[i][j]);
                    acc[i][j] = fmaf(av[i].w, bv[j].w, acc[i][j]);
                }
        }
        __syncthreads();
    }

    // epilogue: bias + vectorized stores (+ kst bf16 restage for z==1)
    float4 bb[2];
    bb[0] = *(const float4*)&B[n0 + tx * 8 + 0];
    bb[1] = *(const float4*)&B[n0 + tx * 8 + 4];
    #pragma unroll
    for (int i = 0; i < 4; ++i) {
        int m = m0 + ty * 4 + i;
        int n = m >> 11, s = m & 2047;
        #pragma unroll
        for (int jj = 0; jj < 2; ++jj) {
            int o0 = n0 + tx * 8 + jj * 4;
            int head = n * NH + (o0 >> 6), e0 = o0 & 63;
            float4 val;
            val.x = acc[i][jj * 4 + 0] + bb[jj].x;
            val.y = acc[i][jj * 4 + 1] + bb[jj].y;
            val.z = acc[i][jj * 4 + 2] + bb[jj].z;
            val.w = acc[i][jj * 4 + 3] + bb[jj].w;
            *(float4*)&out[(size_t)head * 131072 + (size_t)s * EH + e0] = val;
            if (z == 1) {
                u16x4 b4;
                b4[0] = f2b(val.x); b4[1] = f2b(val.y);
                b4[2] = f2b(val.z); b4[3] = f2b(val.w);
                *(u16x4*)&kst[(ty * 4 + i) * 136 + tx * 8 + jj * 4] = b4;
            }
        }
    }

    if (z == 1) {
        __syncthreads();
        const int base_head = (m0 >> 11) * NH + (n0 >> 6);   // first of 2 heads in tile
        const int kt0 = (m0 & 2047) >> 4;
        #pragma unroll
        for (int it = 0; it < 4; ++it) {
            int g = tid + it * 256;                 // 1024 frags: 2 heads x 4 kt x 2 ks x 64 lanes
            int lane_g = g & 63;
            int rest = g >> 6;                      // 0..15
            int head_loc = rest >> 3, ksb = (rest >> 2) & 1, kt = rest & 3;
            int s_loc = kt * 16 + (lane_g & 15);
            int ecol = head_loc * 64 + ksb * 32 + ((lane_g >> 4) << 3);
            u16x8 vv = *(const u16x8*)&kst[s_loc * 136 + ecol];
            size_t idx = ((((size_t)(base_head + head_loc) * 128 + (kt0 + kt)) * 2 + ksb) * 64 + lane_g) * 8;
            *(u16x8*)&khi[idx] = vv;
        }
    }
}

// ---------------------------------------------------------------------------
// Kernel 2: MFMA bf16 approx QK^T -> tau-margin candidates -> exact f32
// rescore -> exact top-32 -> softmax -> A, V.
// Round-9: Nc<=64 fast path = 21-stage u32 bitonic + ballot tie-break
// (replaces 42-stage u64 sort); per-(wave,row) cand buffers; epilogue zeroes
// LDS staging once per wave, clears only scattered entries between rows.
// ---------------------------------------------------------------------------
__device__ __forceinline__ unsigned long long sort64_desc(unsigned long long v, int lane) {
    #pragma unroll
    for (int k = 2; k <= 64; k <<= 1)
        #pragma unroll
        for (int j = k >> 1; j >= 1; j >>= 1) {
            unsigned long long o = __shfl_xor(v, j, 64);
            bool up = ((lane & k) != 0);                 // descending
            bool keepmin = (((lane & j) == 0) == up);
            unsigned long long lo = v < o ? v : o;
            unsigned long long hi = v > o ? v : o;
            v = keepmin ? lo : hi;
        }
    return v;
}
__device__ __forceinline__ unsigned sort32_desc(unsigned v, int lane) {
    #pragma unroll
    for (int k = 2; k <= 64; k <<= 1)
        #pragma unroll
        for (int j = k >> 1; j >= 1; j >>= 1) {
            unsigned o = __shfl_xor(v, j, 64);
            bool up = ((lane & k) != 0);                 // descending
            bool keepmin = (((lane & j) == 0) == up);
            unsigned lo = v < o ? v : o, hi = v > o ? v : o;
            v = keepmin ? lo : hi;
        }
    return v;
}
__device__ __forceinline__ unsigned long long merge_top64(unsigned long long a, unsigned long long b, int lane) {
    unsigned long long br = __shfl(b, 63 - lane, 64);
    unsigned long long m = a > br ? a : br;
    #pragma unroll
    for (int j = 32; j >= 1; j >>= 1) {
        unsigned long long o = __shfl_xor(m, j, 64);
        bool keepmax = ((lane & j) == 0);
        unsigned long long mx = m > o ? m : o;
        unsigned long long mn = m < o ? m : o;
        m = keepmax ? mx : mn;
    }
    return m;
}

__global__ __launch_bounds__(512, 4) void attn_kernel(
    const float* __restrict__ ws, float* __restrict__ outV, float* __restrict__ outA)
{
    const float* qw = ws;
    const float* kw = ws + 2097152;
    const float* vw = ws + 4194304;
    const unsigned short* khi = (const unsigned short*)(ws + 6291456);

    __shared__ unsigned short scores16[2048 * 16];   // 65536 B, [key][row^(key&12)]
    __shared__ float qs[EH * 16];                    // 4096 B, [e][row]
    __shared__ unsigned short candArr[8 * 2 * 192];  // 6144 B, per (wave,row)

    const int tid  = threadIdx.x;
    const int lane = tid & 63;
    const int uwv  = __builtin_amdgcn_readfirstlane(tid) >> 6;  // wave id (SGPR)

    // XCD swizzle: 2048 blocks, 256/XCD = 2 heads per XCD (working set ~3.5MB in L2)
    unsigned bid = blockIdx.x;
    unsigned id  = (bid & 7u) * 256u + (bid >> 3);
    const int head = (int)(id >> 7);           // n*8+h
    const int l0   = (int)(id & 127u) * 16;
    const size_t headoff = (size_t)head * 131072;

    // stage q: qs[e][row], rows l0..l0+15
    #pragma unroll
    for (int it = 0; it < 2; ++it) {
        int i = tid + it * 512;
        int row = i & 15, e = i >> 4;
        qs[i] = qw[headoff + (size_t)(l0 + row) * EH + e];
    }
    __syncthreads();

    // ---- Phase A: MFMA approx scores -> u16 keys in LDS (b64 frag stores) ----
    {
        bf16x8 afrag[2];
        #pragma unroll
        for (int ks = 0; ks < 2; ++ks)
            #pragma unroll
            for (int j = 0; j < 8; ++j) {
                int e = ks * 32 + ((lane >> 4) << 3) + j;
                afrag[ks][j] = (short)f2b(qs[e * 16 + (lane & 15)]);
            }

        #pragma unroll
        for (int kt = 0; kt < 16; ++kt) {
            f32x4 acc = (f32x4)(0.f);
            int ktg = uwv * 16 + kt;
            #pragma unroll
            for (int ks = 0; ks < 2; ++ks) {
                bf16x8 b = *(const bf16x8*)(khi + (size_t)head * 131072 +
                              ((((size_t)ktg * 2 + ks) * 64 + lane) << 3));
                acc = __builtin_amdgcn_mfma_f32_16x16x32_bf16(afrag[ks], b, acc, 0, 0, 0);
            }
            int key = uwv * 256 + kt * 16 + (lane & 15);
            int rbase = (lane >> 4) << 2;          // C: col=lane&15, row=rbase+reg
            int p = rbase ^ (key & 12);            // bank-spread swizzle
            u16x4 s4;
            #pragma unroll
            for (int reg = 0; reg < 4; ++reg)
                s4[reg] = (unsigned short)(f2key(acc[reg]) >> 16);
            *(u16x4*)&scores16[key * 16 + p] = s4;   // one aligned b64 store
        }
    }
    __syncthreads();

    // ---- Select: wave uwv owns rows 2uwv, 2uwv+1; fully wave-local ----
    const unsigned long long lmlt = (1ull << lane) - 1ull;
    int selS[2]; float selW[2];

    // read both rows' keys once: u32 = {row r0, row r0+1} u16 pair
    const int r0 = 2 * uwv;
    unsigned pk[32];
    #pragma unroll
    for (int t = 0; t < 32; ++t) {
        int key = t * 64 + lane;
        int p0 = r0 ^ (key & 12);                  // even; pair-adjacent with r0+1
        pk[t] = *(const unsigned*)&scores16[key * 16 + p0];
    }
    __syncthreads();   // all pk reads done before any wave scribbles abuf below

    #pragma unroll
    for (int rr2 = 0; rr2 < 2; ++rr2) {
        const int lrow = l0 + r0 + rr2;
        unsigned short* cand = candArr + (uwv * 2 + rr2) * 192;

        // 1. per-lane max over this row's 32 keys
        unsigned mx = 0;
        #pragma unroll
        for (int t = 0; t < 32; ++t) {
            unsigned a = rr2 ? (pk[t] >> 16) : (pk[t] & 0xFFFFu);
            mx = umax2(mx, a);
        }
        // 2. bitonic ascending sort of lane maxima; tau16 = rank-32 (lane 32)
        {
            unsigned v = mx;
            #pragma unroll
            for (int k = 2; k <= 64; k <<= 1)
                #pragma unroll
                for (int j = k >> 1; j >= 1; j >>= 1) {
                    unsigned o = __shfl_xor(v, j);
                    bool up = ((lane & k) == 0);
                    bool keepmin = (((lane & j) == 0) == up);
                    unsigned lo = v < o ? v : o, hi = v > o ? v : o;
                    v = keepmin ? lo : hi;
                }
            mx = __shfl(v, 32);
        }
        const unsigned tau16 = mx;
        const float tauf = key2f(tau16 << 16);
        const unsigned thr16 = f2key(tauf - 0.35f) >> 16;   // margin: bf16+trunc error

        // 3. ballot-prefix compaction (ascending global index order)
        int Nc = 0;
        #pragma unroll
        for (int t = 0; t < 32; ++t) {
            unsigned a = rr2 ? (pk[t] >> 16) : (pk[t] & 0xFFFFu);
            bool c = a >= thr16;
            unsigned long long b = __ballot(c);
            if (c) {
                int p = Nc + __popcll(b & lmlt);
                if (p < 192) cand[p] = (unsigned short)(t * 64 + lane);
            }
            Nc += __popcll(b);
        }
        if (Nc > 192) Nc = 192;

        // 4. q row via wave-uniform global loads (scalar broadcast)
        const float* qrow = qw + headoff + (size_t)lrow * EH;
        float4 qv[16];
        #pragma unroll
        for (int c4 = 0; c4 < 16; ++c4) qv[c4] = *(const float4*)&qrow[c4 * 4];

        if (Nc <= 64) {
            // ---- fast path: one chunk, u32 sort + ballot tie-break ----
            bool valid = lane < Nc;
            int si = valid ? (int)cand[lane] : 0;
            const float* krow = kw + headoff + (size_t)si * EH;
            float sc = 0.f;
            #pragma unroll
            for (int c4 = 0; c4 < 16; ++c4) {      // ascending e: bit-identical
                float4 kv = *(const float4*)&krow[c4 * 4];
                sc = fmaf(qv[c4].x, kv.x, sc);
                sc = fmaf(qv[c4].y, kv.y, sc);
                sc = fmaf(qv[c4].z, kv.z, sc);
                sc = fmaf(qv[c4].w, kv.w, sc);
            }
            unsigned k32 = valid ? f2key(sc) : 0u;   // 0 < any real key
            unsigned sorted = sort32_desc(k32, lane);
            const unsigned T   = __builtin_amdgcn_readlane((int)sorted, 31);
            const unsigned M32 = __builtin_amdgcn_readlane((int)sorted, 0);
            unsigned long long bgt = __ballot(k32 > T);
            int needEq = TK - __popcll(bgt);
            unsigned long long beq = __ballot(valid && (k32 == T));
            int eqrank = __popcll(beq & lmlt);       // cand ascending-index => lowest idx first
            bool kept = valid && ((k32 > T) || ((k32 == T) && (eqrank < needEq)));
            const float M = key2f(M32);
            float ee = kept ? __expf(0.125f * (sc - M)) : 0.f;
            float Z = ee;
            #pragma unroll
            for (int d = 1; d < 64; d <<= 1) Z += __shfl_xor(Z, d);
            float w = ee / Z;
            // compact (si, w) to lanes 0..31 via ds_permute push (rank = kept prefix)
            unsigned long long bk = __ballot(kept);
            int rk = __popcll(bk & lmlt);
            int addr = kept ? (rk * 4) : 252;        // non-kept push to dead lane 63
            int psi = __builtin_amdgcn_ds_permute(addr, si);
            int pw  = __builtin_amdgcn_ds_permute(addr, __float_as_int(w));
            selS[rr2] = psi;
            selW[rr2] = __int_as_float(pw);
        } else {
            // ---- fallback: u64 composite chunked sort (rounds 5-8 proven) ----
            const int nch = (Nc + 63) >> 6;
            unsigned long long best = 0ull;
            for (int c = 0; c < nch; ++c) {
                int p = c * 64 + lane;
                bool valid = p < Nc;
                int si = valid ? (int)cand[p] : 0;
                const float* krow = kw + headoff + (size_t)si * EH;
                float sc = 0.f;
                #pragma unroll
                for (int c4 = 0; c4 < 16; ++c4) {
                    float4 kv = *(const float4*)&krow[c4 * 4];
                    sc = fmaf(qv[c4].x, kv.x, sc);
                    sc = fmaf(qv[c4].y, kv.y, sc);
                    sc = fmaf(qv[c4].z, kv.z, sc);
                    sc = fmaf(qv[c4].w, kv.w, sc);
                }
                unsigned long long comp = valid
                    ? ((((unsigned long long)f2key(sc)) << 32) | (unsigned)(~si))
                    : 0ull;
                comp = sort64_desc(comp, lane);
                best = (c == 0) ? comp : merge_top64(best, comp, lane);
            }
            unsigned key32 = (unsigned)(best >> 32);
            int si = (int)(~((unsigned)best)) & 2047;
            float sc = key2f(key32);
            float M = __shfl(sc, 0);
            float ee = (lane < TK) ? __expf(0.125f * (sc - M)) : 0.f;
            float Z = ee;
            #pragma unroll
            for (int d = 1; d < 64; d <<= 1) Z += __shfl_xor(Z, d);
            selS[rr2] = si;
            selW[rr2] = ee / Z;
        }
    }

    // ---- Epilogue: A rows staged in wave-private 8KB LDS + V rows ----
    float* abuf = (float*)((char*)scores16 + uwv * 8192);   // wave-private 2048 f32
    {
        float4* ab4 = (float4*)abuf;
        const float4 z4 = make_float4(0.f, 0.f, 0.f, 0.f);
        #pragma unroll
        for (int u = 0; u < 8; ++u) ab4[u * 64 + lane] = z4;   // zero ONCE per wave
    }
    #pragma unroll
    for (int rr2 = 0; rr2 < 2; ++rr2) {
        const int lrow = l0 + r0 + rr2;
        float4* ab4 = (float4*)abuf;
        if (lane < TK) abuf[selS[rr2]] = selW[rr2];          // wave-local scatter
        float* Arow = outA + ((size_t)head * 2048 + lrow) * 2048;
        #pragma unroll
        for (int u = 0; u < 8; ++u)
            *(float4*)&Arow[(u * 64 + lane) * 4] = ab4[u * 64 + lane];
        if (lane < TK) abuf[selS[rr2]] = 0.f;                // clear only scatters

        // V: broadcast slots via readlane (VALU) -> coalesced loads
        float acc = 0.f;
        int   siv = selS[rr2];
        unsigned wbits = __float_as_uint(selW[rr2]);
        #pragma unroll
        for (int i = 0; i < TK; ++i) {
            int s_i   = __builtin_amdgcn_readlane(siv, i);
            float w_i = __uint_as_float((unsigned)__builtin_amdgcn_readlane((int)wbits, i));
            acc = fmaf(w_i, vw[headoff + (size_t)s_i * EH + lane], acc);
        }
        const int n = head >> 3, h = head & 7;
        outV[((size_t)(n * 2048 + lrow)) * 512 + h * 64 + lane] = acc;
    }
}

// ---------------------------------------------------------------------------
extern "C" void kernel_launch(void* const* d_in, const int* in_sizes, int n_in,
                              void* d_out, int out_size, void* d_ws, size_t ws_size,
                              hipStream_t stream)
{
    (void)in_sizes; (void)n_in; (void)out_size; (void)ws_size;
    const float* q  = (const float*)d_in[0];
    const float* k  = (const float*)d_in[1];
    const float* v  = (const float*)d_in[2];
    const float* Wq = (const float*)d_in[3];
    const float* bq = (const float*)d_in[4];
    const float* Wk = (const float*)d_in[5];
    const float* bk = (const float*)d_in[6];
    const float* Wv = (const float*)d_in[7];
    const float* bv = (const float*)d_in[8];
    float* ws   = (float*)d_ws;  // 28 MiB
    float* outV = (float*)d_out;
    float* outA = outV + (size_t)NBATCH * LSEQ * HD;

    proj_kernel<<<dim3(64, 4, 3), 256, 0, stream>>>(q, k, v, Wq, bq, Wk, bk, Wv, bv, ws);
    attn_kernel<<<dim3(2048, 1, 1), 512, 0, stream>>>(ws, outV, outA);
}